// Round 18
// baseline (24.347 us; speedup 1.0000x reference)
//
#include <hip/hip_runtime.h>
#include <hip/hip_bf16.h>

#define B_ROWS 32768
#define D_IN   128
#define H1_    256
#define HTAU   32
#define NBLK   128

#define NE     64
#define SMIN  (-8.0f)
#define SMAX  ( 8.0f)

typedef __bf16 bf16_t;
typedef bf16_t bf16x8 __attribute__((ext_vector_type(8)));
typedef float  f32x4  __attribute__((ext_vector_type(4)));

__device__ __forceinline__ bf16x8 cvt8(const float* v) {
    bf16x8 r;
#pragma unroll
    for (int i = 0; i < 8; ++i) r[i] = (bf16_t)v[i];
    return r;
}

// async global->LDS, 16B/lane; LDS dest = wave-uniform base + lane*16
__device__ __forceinline__ void gload_lds16(const void* g, void* l) {
    __builtin_amdgcn_global_load_lds(
        (const __attribute__((address_space(1))) uint32_t*)g,
        (__attribute__((address_space(3))) uint32_t*)l, 16, 0, 0);
}

// ---------------------------------------------------------------------------
// prep: blocks [0,128): tau table pairs; blocks [128,176): W -> bf16 frag order
// ---------------------------------------------------------------------------
__global__ void prep(const float* __restrict__ w1, const float* __restrict__ w2,
                     const float* __restrict__ wt1, const float* __restrict__ bt1,
                     const float* __restrict__ wt2, const float* __restrict__ bt2,
                     float2* __restrict__ tab2,
                     bf16x8* __restrict__ w1f, bf16x8* __restrict__ w2f) {
    __shared__ float ps[4][64];
    const int bid = blockIdx.x, tid = threadIdx.x;
    if (bid < NBLK) {
        const int n  = bid;
        const int e  = tid & 63;
        const int hh = tid >> 6;
        float s = SMIN + (SMAX - SMIN) * (float)e / (float)(NE - 1);
        float part = (hh == 0) ? bt2[n] : 0.f;
#pragma unroll
        for (int j = 0; j < 8; ++j) {
            int h = hh * 8 + j;
            float z  = s * wt1[n * HTAU + h] + bt1[n * HTAU + h];
            float sp = (z > 20.f) ? z : log1pf(expf(z));
            part += wt2[n * HTAU + h] * sp;
        }
        ps[hh][e] = part;
        __syncthreads();
        if (hh == 0) {
            float acc = ps[0][e] + ps[1][e] + ps[2][e] + ps[3][e];
            float nxt = __shfl_down(acc, 1, 64);
            tab2[n * NE + e] = make_float2(acc, nxt);
        }
    } else {
        const int cid  = (bid - NBLK) * 256 + tid;
        const int isW2 = cid >= 4096;
        const int c2   = isW2 ? cid - 4096 : cid;
        const int kk = c2 >> 10, c = c2 & 1023;
        const int nf = c >> 6,  ll = c & 63;
        const int col = nf * 16 + (ll & 15);
        const int kr  = kk * 32 + (ll >> 4) * 8;
        const float* src = isW2 ? (w2 + col * H1_ + kr) : (w1 + col * D_IN + kr);
        float tmp[8];
        *(f32x4*)tmp       = *(const f32x4*)src;
        *(f32x4*)(tmp + 4) = *(const f32x4*)(src + 4);
        (isW2 ? w2f : w1f)[c2] = cvt8(tmp);
    }
}

// ---------------------------------------------------------------------------
// fused_main r18: r17 (best: 23.78us) + T5 s_setprio around MFMA clusters.
// Structure unchanged: BM=128, 8 waves, 6 K-64 steps, 3 rotating 32KB
// pair-buffers, counted vmcnt(4) (final step vmcnt(0)), one s_barrier/step,
// wave-private h1 rows. T5 prerequisite (phase-split counted-vmcnt schedule,
// m218b) is now satisfied; prio(1) favors MFMA-entering waves on the SIMD.
// LDS = 96KB wsl + 64KB h1 = 160KB, 1 wg/CU, grid 256.
// ---------------------------------------------------------------------------
__global__ __launch_bounds__(512, 2)
void fused_main(const float* __restrict__ x,
                const bf16x8* __restrict__ w1f, const bf16x8* __restrict__ w2f,
                const float* __restrict__ b1, const float* __restrict__ b2,
                const float* __restrict__ w3, const float* __restrict__ b3,
                const float2* __restrict__ tab2, const float* __restrict__ wlr,
                const float* __restrict__ blr,
                float* __restrict__ mu_out, float* __restrict__ lr_out) {
    __shared__ bf16x8 wsl[6144];          // 3 x 32KB rotating W pair-slices
    __shared__ char   h1_raw[128 * 512];  // 64KB bf16 [128][256], swizzled

    const int tid = threadIdx.x;
    const int l   = tid & 63;
    const int w   = tid >> 6;             // wave 0..7
    const int q   = l >> 4;
    const int l15 = l & 15;
    const int row = w * 16 + l15;         // block-local row 0..127
    const int rb  = blockIdx.x * 128;

    // stage pair p (slices 2p,2p+1; p<2: W1, else W2) into buffer (p%3)
    auto STAGE = [&](int p) {
        const bf16x8* src = (p < 2) ? (w1f + p * 2048) : (w2f + (p - 2) * 2048);
        bf16x8* dst = wsl + (p % 3) * 2048 + w * 256;
#pragma unroll
        for (int j = 0; j < 4; ++j)
            gload_lds16(src + w * 256 + j * 64 + l, dst + j * 64);
    };

    // ---- prologue: issue pairs 0,1; x + tau (all 8 waves, 1 row/lane) ----
    STAGE(0);
    STAGE(1);

    float tsum = 0.f;
    bf16x8 a1[4];
    {
        const float* xr = x + (size_t)(rb + row) * D_IN + q * 8;
        const float* wr = wlr + q * 8;
        const float INVDS = (float)(NE - 1) / (SMAX - SMIN);
#pragma unroll
        for (int kk = 0; kk < 4; ++kk) {
            float t[8], wv[8];
            *(f32x4*)t      = *(const f32x4*)(xr + kk * 32);
            *(f32x4*)(t+4)  = *(const f32x4*)(xr + kk * 32 + 4);
            *(f32x4*)wv     = *(const f32x4*)(wr + kk * 32);
            *(f32x4*)(wv+4) = *(const f32x4*)(wr + kk * 32 + 4);
            a1[kk] = cvt8(t);
#pragma unroll
            for (int i = 0; i < 8; ++i) {
                float s = fminf(fmaxf(t[i], SMIN), SMAX);
                float u = (s - SMIN) * INVDS;
                int ii = (int)u;
                ii = ii > NE - 2 ? NE - 2 : ii;
                float fr = u - (float)ii;
                int n = kk * 32 + q * 8 + i;
                float2 tv = tab2[n * NE + ii];
                tsum += wv[i] * (tv.x + (tv.y - tv.x) * fr);
            }
        }
        tsum += __shfl_xor(tsum, 16, 64);
        tsum += __shfl_xor(tsum, 32, 64);
    }

    f32x4 acc[16];
#pragma unroll
    for (int f = 0; f < 16; ++f) acc[f] = (f32x4){0.f, 0.f, 0.f, 0.f};

    // ---- 6-step pipelined K loop (steps 0,1: layer 1; 2..5: layer 2) ----
#pragma unroll
    for (int s = 0; s < 6; ++s) {
        if (s < 5) {
            asm volatile("s_waitcnt vmcnt(4)" ::: "memory");  // pair s landed
        } else {
            asm volatile("s_waitcnt vmcnt(0)" ::: "memory");  // final drain
        }
        __builtin_amdgcn_sched_barrier(0);
        __builtin_amdgcn_s_barrier();                     // all waves' portions
        const bf16x8* wb = wsl + (s % 3) * 2048;

        if (s < 2) {
            __builtin_amdgcn_s_setprio(1);
#pragma unroll
            for (int kh = 0; kh < 2; ++kh)
#pragma unroll
                for (int nf = 0; nf < 16; ++nf)
                    acc[nf] = __builtin_amdgcn_mfma_f32_16x16x32_bf16(
                        a1[s * 2 + kh], wb[kh * 1024 + nf * 64 + l], acc[nf], 0, 0, 0);
            __builtin_amdgcn_s_setprio(0);
            if (s == 1) {   // h1 = relu(acc+b1) -> LDS (wave-private rows)
#pragma unroll
                for (int f = 0; f < 16; ++f) {
                    int col = f * 16 + l15;
                    float bias = b1[col];
#pragma unroll
                    for (int r = 0; r < 4; ++r) {
                        int gr = w * 16 + q * 4 + r;
                        float v = acc[f][r] + bias;
                        v = v > 0.f ? v : 0.f;
                        int byte = (gr * 512 + col * 2) ^ ((gr & 7) << 4);
                        *(bf16_t*)(h1_raw + byte) = (bf16_t)v;
                    }
                    acc[f] = (f32x4){0.f, 0.f, 0.f, 0.f};
                }
            }
        } else {
            __builtin_amdgcn_s_setprio(1);
#pragma unroll
            for (int kh = 0; kh < 2; ++kh) {
                int k0   = ((s - 2) * 2 + kh) * 32 + q * 8;
                int byte = (row * 512 + k0 * 2) ^ ((row & 7) << 4);
                bf16x8 a = *(bf16x8*)(h1_raw + byte);
#pragma unroll
                for (int nf = 0; nf < 16; ++nf)
                    acc[nf] = __builtin_amdgcn_mfma_f32_16x16x32_bf16(
                        a, wb[kh * 1024 + nf * 64 + l], acc[nf], 0, 0, 0);
            }
            __builtin_amdgcn_s_setprio(0);
        }

        if (s < 4) STAGE(s + 2);          // refill buf((s+2)%3): safe post-MFMA
    }

    // ---- epilogue: mu = relu(acc + b2) . w3 + b3 (per-wave, full cols) ----
    float p[4] = {0.f, 0.f, 0.f, 0.f};
#pragma unroll
    for (int f = 0; f < 16; ++f) {
        int col = f * 16 + l15;
        float bias = b2[col];
        float wv   = w3[col];
#pragma unroll
        for (int r = 0; r < 4; ++r) {
            float v = acc[f][r] + bias;
            v = v > 0.f ? v : 0.f;
            p[r] += v * wv;
        }
    }
#pragma unroll
    for (int m = 1; m < 16; m <<= 1) {
#pragma unroll
        for (int r = 0; r < 4; ++r) p[r] += __shfl_xor(p[r], m, 64);
    }
    if (l15 == 0) {
        float bb = b3[0];
#pragma unroll
        for (int r = 0; r < 4; ++r)
            mu_out[rb + w * 16 + q * 4 + r] = p[r] + bb;
    }
    // deferred tau store (barrier-free tail)
    if (q == 0) lr_out[rb + row] = tsum + blr[0];
}

extern "C" void kernel_launch(void* const* d_in, const int* in_sizes, int n_in,
                              void* d_out, int out_size, void* d_ws, size_t ws_size,
                              hipStream_t stream) {
    const float* x   = (const float*)d_in[0];
    const float* w1  = (const float*)d_in[1];
    const float* b1  = (const float*)d_in[2];
    const float* w2  = (const float*)d_in[3];
    const float* b2  = (const float*)d_in[4];
    const float* w3  = (const float*)d_in[5];
    const float* b3  = (const float*)d_in[6];
    const float* wt1 = (const float*)d_in[7];
    const float* bt1 = (const float*)d_in[8];
    const float* wt2 = (const float*)d_in[9];
    const float* bt2 = (const float*)d_in[10];
    const float* wlr = (const float*)d_in[11];
    const float* blr = (const float*)d_in[12];

    float* out    = (float*)d_out;
    float* mu_out = out;                 // output 0: mu     [32768]
    float* lr_out = out + B_ROWS;        // output 1: out_lr [32768]

    char* ws = (char*)d_ws;
    float2* tab2 = (float2*)ws;                   // 64KB
    bf16x8* w1f  = (bf16x8*)(ws + (64 << 10));    // 64KB
    bf16x8* w2f  = (bf16x8*)(ws + (128 << 10));   // 128KB

    prep<<<NBLK + 48, 256, 0, stream>>>(w1, w2, wt1, bt1, wt2, bt2, tab2, w1f, w2f);
    fused_main<<<B_ROWS / 128, 512, 0, stream>>>(x, w1f, w2f, b1, b2, w3, b3,
                                                 tab2, wlr, blr, mu_out, lr_out);
}

// Round 19
// 23.597 us; speedup vs baseline: 1.0318x; 1.0318x over previous
//
#include <hip/hip_runtime.h>
#include <hip/hip_bf16.h>

#define B_ROWS 32768
#define D_IN   128
#define H1_    256
#define HTAU   32
#define NBLK   128

#define NE     64
#define SMIN  (-8.0f)
#define SMAX  ( 8.0f)

typedef __bf16 bf16_t;
typedef bf16_t bf16x8 __attribute__((ext_vector_type(8)));
typedef float  f32x4  __attribute__((ext_vector_type(4)));

__device__ __forceinline__ bf16x8 cvt8(const float* v) {
    bf16x8 r;
#pragma unroll
    for (int i = 0; i < 8; ++i) r[i] = (bf16_t)v[i];
    return r;
}

// async global->LDS, 16B/lane; LDS dest = wave-uniform base + lane*16
__device__ __forceinline__ void gload_lds16(const void* g, void* l) {
    __builtin_amdgcn_global_load_lds(
        (const __attribute__((address_space(1))) uint32_t*)g,
        (__attribute__((address_space(3))) uint32_t*)l, 16, 0, 0);
}

// ---------------------------------------------------------------------------
// prep: blocks [0,128): tau table pairs; blocks [128,176): W -> bf16 frag order
// ---------------------------------------------------------------------------
__global__ void prep(const float* __restrict__ w1, const float* __restrict__ w2,
                     const float* __restrict__ wt1, const float* __restrict__ bt1,
                     const float* __restrict__ wt2, const float* __restrict__ bt2,
                     float2* __restrict__ tab2,
                     bf16x8* __restrict__ w1f, bf16x8* __restrict__ w2f) {
    __shared__ float ps[4][64];
    const int bid = blockIdx.x, tid = threadIdx.x;
    if (bid < NBLK) {
        const int n  = bid;
        const int e  = tid & 63;
        const int hh = tid >> 6;
        float s = SMIN + (SMAX - SMIN) * (float)e / (float)(NE - 1);
        float part = (hh == 0) ? bt2[n] : 0.f;
#pragma unroll
        for (int j = 0; j < 8; ++j) {
            int h = hh * 8 + j;
            float z  = s * wt1[n * HTAU + h] + bt1[n * HTAU + h];
            float sp = (z > 20.f) ? z : log1pf(expf(z));
            part += wt2[n * HTAU + h] * sp;
        }
        ps[hh][e] = part;
        __syncthreads();
        if (hh == 0) {
            float acc = ps[0][e] + ps[1][e] + ps[2][e] + ps[3][e];
            float nxt = __shfl_down(acc, 1, 64);
            tab2[n * NE + e] = make_float2(acc, nxt);
        }
    } else {
        const int cid  = (bid - NBLK) * 256 + tid;
        const int isW2 = cid >= 4096;
        const int c2   = isW2 ? cid - 4096 : cid;
        const int kk = c2 >> 10, c = c2 & 1023;
        const int nf = c >> 6,  ll = c & 63;
        const int col = nf * 16 + (ll & 15);
        const int kr  = kk * 32 + (ll >> 4) * 8;
        const float* src = isW2 ? (w2 + col * H1_ + kr) : (w1 + col * D_IN + kr);
        float tmp[8];
        *(f32x4*)tmp       = *(const f32x4*)src;
        *(f32x4*)(tmp + 4) = *(const f32x4*)(src + 4);
        (isW2 ? w2f : w1f)[c2] = cvt8(tmp);
    }
}

// ---------------------------------------------------------------------------
// fused_main (r17 revert, best known: 23.78us): BM=128, 8 waves, 6 K-64
// steps, 3 rotating 32KB pair-buffers, counted vmcnt(4) (final step
// vmcnt(0)), one s_barrier per step, wave-private h1 rows.
// r18 showed setprio regresses here (lockstep waves within each phase).
// LDS = 96KB wsl + 64KB h1 = 160KB, 1 wg/CU, grid 256.
// ---------------------------------------------------------------------------
__global__ __launch_bounds__(512, 2)
void fused_main(const float* __restrict__ x,
                const bf16x8* __restrict__ w1f, const bf16x8* __restrict__ w2f,
                const float* __restrict__ b1, const float* __restrict__ b2,
                const float* __restrict__ w3, const float* __restrict__ b3,
                const float2* __restrict__ tab2, const float* __restrict__ wlr,
                const float* __restrict__ blr,
                float* __restrict__ mu_out, float* __restrict__ lr_out) {
    __shared__ bf16x8 wsl[6144];          // 3 x 32KB rotating W pair-slices
    __shared__ char   h1_raw[128 * 512];  // 64KB bf16 [128][256], swizzled

    const int tid = threadIdx.x;
    const int l   = tid & 63;
    const int w   = tid >> 6;             // wave 0..7
    const int q   = l >> 4;
    const int l15 = l & 15;
    const int row = w * 16 + l15;         // block-local row 0..127
    const int rb  = blockIdx.x * 128;

    // stage pair p (slices 2p,2p+1; p<2: W1, else W2) into buffer (p%3)
    auto STAGE = [&](int p) {
        const bf16x8* src = (p < 2) ? (w1f + p * 2048) : (w2f + (p - 2) * 2048);
        bf16x8* dst = wsl + (p % 3) * 2048 + w * 256;
#pragma unroll
        for (int j = 0; j < 4; ++j)
            gload_lds16(src + w * 256 + j * 64 + l, dst + j * 64);
    };

    // ---- prologue: issue pairs 0,1; x + tau (all 8 waves, 1 row/lane) ----
    STAGE(0);
    STAGE(1);

    float tsum = 0.f;
    bf16x8 a1[4];
    {
        const float* xr = x + (size_t)(rb + row) * D_IN + q * 8;
        const float* wr = wlr + q * 8;
        const float INVDS = (float)(NE - 1) / (SMAX - SMIN);
#pragma unroll
        for (int kk = 0; kk < 4; ++kk) {
            float t[8], wv[8];
            *(f32x4*)t      = *(const f32x4*)(xr + kk * 32);
            *(f32x4*)(t+4)  = *(const f32x4*)(xr + kk * 32 + 4);
            *(f32x4*)wv     = *(const f32x4*)(wr + kk * 32);
            *(f32x4*)(wv+4) = *(const f32x4*)(wr + kk * 32 + 4);
            a1[kk] = cvt8(t);
#pragma unroll
            for (int i = 0; i < 8; ++i) {
                float s = fminf(fmaxf(t[i], SMIN), SMAX);
                float u = (s - SMIN) * INVDS;
                int ii = (int)u;
                ii = ii > NE - 2 ? NE - 2 : ii;
                float fr = u - (float)ii;
                int n = kk * 32 + q * 8 + i;
                float2 tv = tab2[n * NE + ii];
                tsum += wv[i] * (tv.x + (tv.y - tv.x) * fr);
            }
        }
        tsum += __shfl_xor(tsum, 16, 64);
        tsum += __shfl_xor(tsum, 32, 64);
    }

    f32x4 acc[16];
#pragma unroll
    for (int f = 0; f < 16; ++f) acc[f] = (f32x4){0.f, 0.f, 0.f, 0.f};

    // ---- 6-step pipelined K loop (steps 0,1: layer 1; 2..5: layer 2) ----
#pragma unroll
    for (int s = 0; s < 6; ++s) {
        if (s < 5) {
            asm volatile("s_waitcnt vmcnt(4)" ::: "memory");  // pair s landed
        } else {
            asm volatile("s_waitcnt vmcnt(0)" ::: "memory");  // final drain
        }
        __builtin_amdgcn_sched_barrier(0);
        __builtin_amdgcn_s_barrier();                     // all waves' portions
        const bf16x8* wb = wsl + (s % 3) * 2048;

        if (s < 2) {
#pragma unroll
            for (int kh = 0; kh < 2; ++kh)
#pragma unroll
                for (int nf = 0; nf < 16; ++nf)
                    acc[nf] = __builtin_amdgcn_mfma_f32_16x16x32_bf16(
                        a1[s * 2 + kh], wb[kh * 1024 + nf * 64 + l], acc[nf], 0, 0, 0);
            if (s == 1) {   // h1 = relu(acc+b1) -> LDS (wave-private rows)
#pragma unroll
                for (int f = 0; f < 16; ++f) {
                    int col = f * 16 + l15;
                    float bias = b1[col];
#pragma unroll
                    for (int r = 0; r < 4; ++r) {
                        int gr = w * 16 + q * 4 + r;
                        float v = acc[f][r] + bias;
                        v = v > 0.f ? v : 0.f;
                        int byte = (gr * 512 + col * 2) ^ ((gr & 7) << 4);
                        *(bf16_t*)(h1_raw + byte) = (bf16_t)v;
                    }
                    acc[f] = (f32x4){0.f, 0.f, 0.f, 0.f};
                }
            }
        } else {
#pragma unroll
            for (int kh = 0; kh < 2; ++kh) {
                int k0   = ((s - 2) * 2 + kh) * 32 + q * 8;
                int byte = (row * 512 + k0 * 2) ^ ((row & 7) << 4);
                bf16x8 a = *(bf16x8*)(h1_raw + byte);
#pragma unroll
                for (int nf = 0; nf < 16; ++nf)
                    acc[nf] = __builtin_amdgcn_mfma_f32_16x16x32_bf16(
                        a, wb[kh * 1024 + nf * 64 + l], acc[nf], 0, 0, 0);
            }
        }

        if (s < 4) STAGE(s + 2);          // refill buf((s+2)%3): safe post-MFMA
    }

    // ---- epilogue: mu = relu(acc + b2) . w3 + b3 (per-wave, full cols) ----
    float p[4] = {0.f, 0.f, 0.f, 0.f};
#pragma unroll
    for (int f = 0; f < 16; ++f) {
        int col = f * 16 + l15;
        float bias = b2[col];
        float wv   = w3[col];
#pragma unroll
        for (int r = 0; r < 4; ++r) {
            float v = acc[f][r] + bias;
            v = v > 0.f ? v : 0.f;
            p[r] += v * wv;
        }
    }
#pragma unroll
    for (int m = 1; m < 16; m <<= 1) {
#pragma unroll
        for (int r = 0; r < 4; ++r) p[r] += __shfl_xor(p[r], m, 64);
    }
    if (l15 == 0) {
        float bb = b3[0];
#pragma unroll
        for (int r = 0; r < 4; ++r)
            mu_out[rb + w * 16 + q * 4 + r] = p[r] + bb;
    }
    // deferred tau store (barrier-free tail)
    if (q == 0) lr_out[rb + row] = tsum + blr[0];
}

extern "C" void kernel_launch(void* const* d_in, const int* in_sizes, int n_in,
                              void* d_out, int out_size, void* d_ws, size_t ws_size,
                              hipStream_t stream) {
    const float* x   = (const float*)d_in[0];
    const float* w1  = (const float*)d_in[1];
    const float* b1  = (const float*)d_in[2];
    const float* w2  = (const float*)d_in[3];
    const float* b2  = (const float*)d_in[4];
    const float* w3  = (const float*)d_in[5];
    const float* b3  = (const float*)d_in[6];
    const float* wt1 = (const float*)d_in[7];
    const float* bt1 = (const float*)d_in[8];
    const float* wt2 = (const float*)d_in[9];
    const float* bt2 = (const float*)d_in[10];
    const float* wlr = (const float*)d_in[11];
    const float* blr = (const float*)d_in[12];

    float* out    = (float*)d_out;
    float* mu_out = out;                 // output 0: mu     [32768]
    float* lr_out = out + B_ROWS;        // output 1: out_lr [32768]

    char* ws = (char*)d_ws;
    float2* tab2 = (float2*)ws;                   // 64KB
    bf16x8* w1f  = (bf16x8*)(ws + (64 << 10));    // 64KB
    bf16x8* w2f  = (bf16x8*)(ws + (128 << 10));   // 128KB

    prep<<<NBLK + 48, 256, 0, stream>>>(w1, w2, wt1, bt1, wt2, bt2, tab2, w1f, w2f);
    fused_main<<<B_ROWS / 128, 512, 0, stream>>>(x, w1f, w2f, b1, b2, w3, b3,
                                                 tab2, wlr, blr, mu_out, lr_out);
}